// Round 1
// baseline (921.589 us; speedup 1.0000x reference)
//
#include <hip/hip_runtime.h>
#include <cstdint>

typedef __attribute__((ext_vector_type(8))) short short8;
typedef __attribute__((ext_vector_type(4))) float float4v;

#define S_LEN 2048
#define HIDDIM 4096

static __device__ __forceinline__ unsigned short f2bf(float f) {
  unsigned int u = __float_as_uint(f);
  unsigned int r = (u + 0x7FFFu + ((u >> 16) & 1u)) >> 16;
  return (unsigned short)r;
}
static __device__ __forceinline__ float bf2f(unsigned short h) {
  return __uint_as_float(((unsigned int)h) << 16);
}

static __device__ __forceinline__ void gload16(const void* gp, void* lp) {
  __builtin_amdgcn_global_load_lds(
      (const __attribute__((address_space(1))) void*)gp,
      (__attribute__((address_space(3))) void*)lp, 16, 0, 0);
}

// ---------------------------------------------------------------- cast f32->bf16
__global__ __launch_bounds__(256) void cast_all(
    const float* __restrict__ s0, const float* __restrict__ s1,
    const float* __restrict__ s2, const float* __restrict__ s3,
    const float* __restrict__ s4,
    unsigned short* __restrict__ d0, unsigned short* __restrict__ d1,
    unsigned short* __restrict__ d2, unsigned short* __restrict__ d3,
    unsigned short* __restrict__ d4) {
  // region sizes in float4 units
  const long n0 = 2097152, n1 = 4194304, n2 = 1048576, n3 = 1048576, n4 = 4194304;
  const long total = n0 + n1 + n2 + n3 + n4;  // 12582912
  for (long i = (long)blockIdx.x * 256 + threadIdx.x; i < total;
       i += (long)gridDim.x * 256) {
    const float* src; unsigned short* dst; long j = i;
    if (j < n0) { src = s0; dst = d0; }
    else if ((j -= n0) < n1) { src = s1; dst = d1; }
    else if ((j -= n1) < n2) { src = s2; dst = d2; }
    else if ((j -= n2) < n3) { src = s3; dst = d3; }
    else { j -= n3; src = s4; dst = d4; }
    float4 v = reinterpret_cast<const float4*>(src)[j];
    ushort4 o;
    o.x = f2bf(v.x); o.y = f2bf(v.y); o.z = f2bf(v.z); o.w = f2bf(v.w);
    reinterpret_cast<ushort4*>(dst)[j] = o;
  }
}

// ---------------------------------------------------------------- GEMM core
// C[M,N] = A[M,K] * B[N,K]^T, K=4096, 128x128 tile, BK=32, 4 waves (2x2),
// 16x16x32 bf16 MFMA, global_load_lds staging, 2-phase double buffer.
__device__ __forceinline__ void gemm128_core(
    const unsigned short* __restrict__ A, const unsigned short* __restrict__ B,
    int mr0, int nc0, unsigned short* As, unsigned short* Bs,
    float4v acc[4][4]) {
  const int t = threadIdx.x;
  const int lane = t & 63;
  const int wid = t >> 6;
  const int wm = wid >> 1, wn = wid & 1;
  const int row = t >> 2, kc = (t & 3) * 8;

#pragma unroll
  for (int i = 0; i < 4; i++)
#pragma unroll
    for (int j = 0; j < 4; j++) acc[i][j] = (float4v){0.f, 0.f, 0.f, 0.f};

  // stage k-tile k0 into buffer buf
  auto stage = [&](int buf, int k0) {
    const unsigned short* ga = A + (long)(mr0 + row) * 4096 + k0 + kc;
    unsigned short* as = As + buf * 4096;
    gload16(ga, as + t * 8);
    gload16(ga + (long)64 * 4096, as + 2048 + t * 8);
    const unsigned short* gb = B + (long)(nc0 + row) * 4096 + k0 + kc;
    unsigned short* bs = Bs + buf * 4096;
    gload16(gb, bs + t * 8);
    gload16(gb + (long)64 * 4096, bs + 2048 + t * 8);
  };

  stage(0, 0);
  __syncthreads();
  for (int kt = 0; kt < 128; ++kt) {
    const int cur = kt & 1;
    if (kt + 1 < 128) stage(cur ^ 1, (kt + 1) * 32);
    const unsigned short* ab =
        As + cur * 4096 + (wm * 64 + (lane & 15)) * 32 + (lane >> 4) * 8;
    const unsigned short* bb =
        Bs + cur * 4096 + (wn * 64 + (lane & 15)) * 32 + (lane >> 4) * 8;
    short8 af[4], bfr[4];
#pragma unroll
    for (int i = 0; i < 4; i++) af[i] = *(const short8*)(ab + i * 512);
#pragma unroll
    for (int i = 0; i < 4; i++) bfr[i] = *(const short8*)(bb + i * 512);
#pragma unroll
    for (int mi = 0; mi < 4; mi++)
#pragma unroll
      for (int ni = 0; ni < 4; ni++)
        acc[mi][ni] = __builtin_amdgcn_mfma_f32_16x16x32_bf16(
            af[mi], bfr[ni], acc[mi][ni], 0, 0, 0);
    __syncthreads();
  }
}

// ---------------------------------------------------------------- QKV projection
__global__ __launch_bounds__(256) void gemm_qkv(
    const unsigned short* __restrict__ A,   // hidden bf16 2048x4096
    const unsigned short* __restrict__ Wq,  // 4096x4096
    const unsigned short* __restrict__ Wk,  // 1024x4096
    const unsigned short* __restrict__ Wv,  // 1024x4096
    unsigned short* __restrict__ Qb,        // 2048x4096
    unsigned short* __restrict__ Kb,        // 2048x1024
    unsigned short* __restrict__ Vt) {      // 1024x2048 (transposed V)
  __shared__ unsigned short As[2 * 4096];
  __shared__ unsigned short Bs[2 * 4096];
  const int nb = blockIdx.x, mb = blockIdx.y;
  const unsigned short* Bp;
  int col0, mode;
  if (nb < 32)      { Bp = Wq; col0 = nb * 128;        mode = 0; }
  else if (nb < 40) { Bp = Wk; col0 = (nb - 32) * 128; mode = 1; }
  else              { Bp = Wv; col0 = (nb - 40) * 128; mode = 2; }
  const int mr0 = mb * 128;

  float4v acc[4][4];
  gemm128_core(A, Bp, mr0, col0, As, Bs, acc);

  const int lane = threadIdx.x & 63;
  const int wid = threadIdx.x >> 6;
  const int wm = wid >> 1, wn = wid & 1;
  const int lr = (lane >> 4) * 4, lc = lane & 15;
#pragma unroll
  for (int mi = 0; mi < 4; mi++)
#pragma unroll
    for (int ni = 0; ni < 4; ni++)
#pragma unroll
      for (int r = 0; r < 4; r++) {
        const int grow = mr0 + wm * 64 + mi * 16 + lr + r;
        const int gcol = col0 + wn * 64 + ni * 16 + lc;
        const unsigned short hv = f2bf(acc[mi][ni][r]);
        if (mode == 0)      Qb[(long)grow * 4096 + gcol] = hv;
        else if (mode == 1) Kb[(long)grow * 1024 + gcol] = hv;
        else                Vt[(long)gcol * 2048 + grow] = hv;
      }
}

// ---------------------------------------------------------------- output projection
__global__ __launch_bounds__(256) void gemm_out(
    const unsigned short* __restrict__ A,   // attn out bf16 2048x4096
    const unsigned short* __restrict__ W,   // Wo bf16 4096x4096
    float* __restrict__ C) {                // 2048x4096 f32
  __shared__ unsigned short As[2 * 4096];
  __shared__ unsigned short Bs[2 * 4096];
  const int nb = blockIdx.x, mb = blockIdx.y;
  const int col0 = nb * 128, mr0 = mb * 128;
  float4v acc[4][4];
  gemm128_core(A, W, mr0, col0, As, Bs, acc);
  const int lane = threadIdx.x & 63;
  const int wid = threadIdx.x >> 6;
  const int wm = wid >> 1, wn = wid & 1;
  const int lr = (lane >> 4) * 4, lc = lane & 15;
#pragma unroll
  for (int mi = 0; mi < 4; mi++)
#pragma unroll
    for (int ni = 0; ni < 4; ni++)
#pragma unroll
      for (int r = 0; r < 4; r++) {
        const int grow = mr0 + wm * 64 + mi * 16 + lr + r;
        const int gcol = col0 + wn * 64 + ni * 16 + lc;
        C[(long)grow * 4096 + gcol] = acc[mi][ni][r];
      }
}

// ---------------------------------------------------------------- RoPE (in place)
__global__ __launch_bounds__(256) void rope_kernel(
    unsigned short* __restrict__ Qb, unsigned short* __restrict__ Kb,
    const float* __restrict__ cosp, const float* __restrict__ sinp) {
  const long i = (long)blockIdx.x * 256 + threadIdx.x;
  unsigned short* buf;
  int nh;
  long j = i;
  if (j < 4194304) { buf = Qb; nh = 32; }
  else { j -= 4194304; buf = Kb; nh = 8; }
  const int d = (int)(j & 63);
  const long tmp = j >> 6;
  const int h = (int)(tmp % nh);
  const int s = (int)(tmp / nh);
  const long base = (long)s * nh * 128 + h * 128 + d;
  const float c = cosp[s * 128 + d];
  const float sn = sinp[s * 128 + d];
  const float x1 = bf2f(buf[base]);
  const float x2 = bf2f(buf[base + 64]);
  buf[base] = f2bf(x1 * c - x2 * sn);
  buf[base + 64] = f2bf(x2 * c + x1 * sn);
}

// ---------------------------------------------------------------- flash attention
// grid: 32 heads x 32 q-tiles (64 rows). block: 4 waves, each owns 16 q rows.
__global__ __launch_bounds__(256) void attn_kernel(
    const unsigned short* __restrict__ Q,   // 2048x4096 (roped)
    const unsigned short* __restrict__ K,   // 2048x1024 (roped)
    const unsigned short* __restrict__ Vt,  // 1024x2048
    unsigned short* __restrict__ AO) {      // 2048x4096
  __shared__ unsigned short P_lds[4][16][72];  // per wave, padded (stride 144B)
  const int t = threadIdx.x, lane = t & 63, w = t >> 6;
  const int bx = blockIdx.x;
  const int hq = bx >> 5;
  const int qt = bx & 31;
  const int hkv = hq >> 2;
  const int qr0 = qt * 64 + w * 16;  // this wave's 16 q rows
  const int lc = lane & 15, lg = lane >> 4;
  const float scale = 0.08838834764831845f;  // 1/sqrt(128)

  // Q fragments (hoisted)
  short8 aq[4];
  const unsigned short* qbase = Q + (long)(qr0 + lc) * 4096 + hq * 128 + lg * 8;
#pragma unroll
  for (int kk = 0; kk < 4; kk++) aq[kk] = *(const short8*)(qbase + kk * 32);

  float m_i[4], l_i[4];
  float4v acc_o[8];
#pragma unroll
  for (int r = 0; r < 4; r++) { m_i[r] = -1e30f; l_i[r] = 0.f; }
#pragma unroll
  for (int n = 0; n < 8; n++) acc_o[n] = (float4v){0.f, 0.f, 0.f, 0.f};

  const int kv_end = qt * 64 + 64;
  for (int c0 = 0; c0 < kv_end; c0 += 64) {
    // ---- S = Q K^T (16x64)
    float4v accs[4];
#pragma unroll
    for (int n = 0; n < 4; n++) accs[n] = (float4v){0.f, 0.f, 0.f, 0.f};
#pragma unroll
    for (int n = 0; n < 4; n++) {
      const unsigned short* kbase =
          K + (long)(c0 + n * 16 + lc) * 1024 + hkv * 128 + lg * 8;
#pragma unroll
      for (int kk = 0; kk < 4; kk++) {
        short8 bk = *(const short8*)(kbase + kk * 32);
        accs[n] = __builtin_amdgcn_mfma_f32_16x16x32_bf16(aq[kk], bk, accs[n], 0, 0, 0);
      }
    }
    // ---- scale + causal mask
#pragma unroll
    for (int n = 0; n < 4; n++) {
      const int gcol = c0 + n * 16 + lc;
#pragma unroll
      for (int r = 0; r < 4; r++) {
        const int grow = qr0 + lg * 4 + r;
        const float sv = accs[n][r] * scale;
        accs[n][r] = (gcol > grow) ? -1e30f : sv;
      }
    }
    // ---- online softmax (rows live in 16-lane groups)
    float sc[4];
#pragma unroll
    for (int r = 0; r < 4; r++) {
      float vm = fmaxf(fmaxf(accs[0][r], accs[1][r]), fmaxf(accs[2][r], accs[3][r]));
#pragma unroll
      for (int x = 1; x < 16; x <<= 1) vm = fmaxf(vm, __shfl_xor(vm, x, 64));
      const float mn = fmaxf(m_i[r], vm);
      sc[r] = __expf(m_i[r] - mn);
      m_i[r] = mn;
      float rs = 0.f;
#pragma unroll
      for (int n = 0; n < 4; n++) {
        const float pv = __expf(accs[n][r] - mn);
        accs[n][r] = pv;
        rs += pv;
      }
#pragma unroll
      for (int x = 1; x < 16; x <<= 1) rs += __shfl_xor(rs, x, 64);
      l_i[r] = l_i[r] * sc[r] + rs;
    }
#pragma unroll
    for (int n = 0; n < 8; n++)
#pragma unroll
      for (int r = 0; r < 4; r++) acc_o[n][r] *= sc[r];
    // ---- P -> LDS (bf16), per-wave private (in-order DS pipe, no barrier)
#pragma unroll
    for (int n = 0; n < 4; n++)
#pragma unroll
      for (int r = 0; r < 4; r++)
        P_lds[w][lg * 4 + r][n * 16 + lc] = f2bf(accs[n][r]);
    // ---- O += P V
#pragma unroll
    for (int kk = 0; kk < 2; kk++) {
      short8 ap = *(const short8*)&P_lds[w][lc][kk * 32 + lg * 8];
#pragma unroll
      for (int nd = 0; nd < 8; nd++) {
        const unsigned short* vb =
            Vt + (long)(hkv * 128 + nd * 16 + lc) * 2048 + c0 + kk * 32 + lg * 8;
        short8 bv = *(const short8*)vb;
        acc_o[nd] = __builtin_amdgcn_mfma_f32_16x16x32_bf16(ap, bv, acc_o[nd], 0, 0, 0);
      }
    }
  }
  // ---- epilogue
#pragma unroll
  for (int nd = 0; nd < 8; nd++)
#pragma unroll
    for (int r = 0; r < 4; r++) {
      const float o = acc_o[nd][r] / l_i[r];
      const int grow = qr0 + lg * 4 + r;
      AO[(long)grow * 4096 + hq * 128 + nd * 16 + lc] = f2bf(o);
    }
}

// ---------------------------------------------------------------- launch
extern "C" void kernel_launch(void* const* d_in, const int* in_sizes, int n_in,
                              void* d_out, int out_size, void* d_ws, size_t ws_size,
                              hipStream_t stream) {
  const float* hidden = (const float*)d_in[0];
  const float* cosp   = (const float*)d_in[1];
  const float* sinp   = (const float*)d_in[2];
  // d_in[3] = attention_mask (pure causal, implemented analytically)
  const float* Wq = (const float*)d_in[4];
  const float* Wk = (const float*)d_in[5];
  const float* Wv = (const float*)d_in[6];
  const float* Wo = (const float*)d_in[7];
  float* out = (float*)d_out;

  char* ws = (char*)d_ws;
  unsigned short* hidB = (unsigned short*)(ws + 0);          // 16 MiB
  unsigned short* WqB  = (unsigned short*)(ws + 16777216);   // 32 MiB
  unsigned short* WkB  = (unsigned short*)(ws + 50331648);   // 8 MiB
  unsigned short* WvB  = (unsigned short*)(ws + 58720256);   // 8 MiB
  unsigned short* WoB  = (unsigned short*)(ws + 67108864);   // 32 MiB
  unsigned short* Qb   = (unsigned short*)(ws + 100663296);  // 16 MiB
  unsigned short* Kb   = (unsigned short*)(ws + 117440512);  // 4 MiB
  unsigned short* VtB  = (unsigned short*)(ws + 121634816);  // 4 MiB
  unsigned short* AO   = (unsigned short*)(ws + 125829120);  // 16 MiB
  // total 142,606,336 bytes

  cast_all<<<2048, 256, 0, stream>>>(hidden, Wq, Wk, Wv, Wo,
                                     hidB, WqB, WkB, WvB, WoB);
  gemm_qkv<<<dim3(48, 16), 256, 0, stream>>>(hidB, WqB, WkB, WvB, Qb, Kb, VtB);
  rope_kernel<<<20480, 256, 0, stream>>>(Qb, Kb, cosp, sinp);
  attn_kernel<<<1024, 256, 0, stream>>>(Qb, Kb, VtB, AO);
  gemm_out<<<dim3(32, 16), 256, 0, stream>>>(AO, WoB, out);
}

// Round 2
// 573.985 us; speedup vs baseline: 1.6056x; 1.6056x over previous
//
#include <hip/hip_runtime.h>
#include <cstdint>

typedef __attribute__((ext_vector_type(8))) short short8;
typedef __attribute__((ext_vector_type(4))) float float4v;

#define S_LEN 2048
#define HIDDIM 4096

static __device__ __forceinline__ unsigned short f2bf(float f) {
  unsigned int u = __float_as_uint(f);
  unsigned int r = (u + 0x7FFFu + ((u >> 16) & 1u)) >> 16;
  return (unsigned short)r;
}
static __device__ __forceinline__ float bf2f(unsigned short h) {
  return __uint_as_float(((unsigned int)h) << 16);
}

static __device__ __forceinline__ void gload16(const void* gp, void* lp) {
  __builtin_amdgcn_global_load_lds(
      (const __attribute__((address_space(1))) void*)gp,
      (__attribute__((address_space(3))) void*)lp, 16, 0, 0);
}

// ---------------------------------------------------------------- cast f32->bf16
__global__ __launch_bounds__(256) void cast_all(
    const float* __restrict__ s0, const float* __restrict__ s1,
    const float* __restrict__ s2, const float* __restrict__ s3,
    const float* __restrict__ s4,
    unsigned short* __restrict__ d0, unsigned short* __restrict__ d1,
    unsigned short* __restrict__ d2, unsigned short* __restrict__ d3,
    unsigned short* __restrict__ d4) {
  const long n0 = 2097152, n1 = 4194304, n2 = 1048576, n3 = 1048576, n4 = 4194304;
  const long total = n0 + n1 + n2 + n3 + n4;  // 12582912
  for (long i = (long)blockIdx.x * 256 + threadIdx.x; i < total;
       i += (long)gridDim.x * 256) {
    const float* src; unsigned short* dst; long j = i;
    if (j < n0) { src = s0; dst = d0; }
    else if ((j -= n0) < n1) { src = s1; dst = d1; }
    else if ((j -= n1) < n2) { src = s2; dst = d2; }
    else if ((j -= n2) < n3) { src = s3; dst = d3; }
    else { j -= n3; src = s4; dst = d4; }
    float4 v = reinterpret_cast<const float4*>(src)[j];
    ushort4 o;
    o.x = f2bf(v.x); o.y = f2bf(v.y); o.z = f2bf(v.z); o.w = f2bf(v.w);
    reinterpret_cast<ushort4*>(dst)[j] = o;
  }
}

// ---------------------------------------------------------------- GEMM core
// C[M,N] = A[M,K] * B[N,K]^T, K=4096, 128x128 tile, BK=32, 4 waves (2x2),
// 16x16x32 bf16 MFMA, global_load_lds staging, 2-phase double buffer.
__device__ __forceinline__ void gemm128_core(
    const unsigned short* __restrict__ A, const unsigned short* __restrict__ B,
    int mr0, int nc0, unsigned short* As, unsigned short* Bs,
    float4v acc[4][4]) {
  const int t = threadIdx.x;
  const int lane = t & 63;
  const int wid = t >> 6;
  const int wm = wid >> 1, wn = wid & 1;
  const int row = t >> 2, kc = (t & 3) * 8;

#pragma unroll
  for (int i = 0; i < 4; i++)
#pragma unroll
    for (int j = 0; j < 4; j++) acc[i][j] = (float4v){0.f, 0.f, 0.f, 0.f};

  auto stage = [&](int buf, int k0) {
    const unsigned short* ga = A + (long)(mr0 + row) * 4096 + k0 + kc;
    unsigned short* as = As + buf * 4096;
    gload16(ga, as + t * 8);
    gload16(ga + (long)64 * 4096, as + 2048 + t * 8);
    const unsigned short* gb = B + (long)(nc0 + row) * 4096 + k0 + kc;
    unsigned short* bs = Bs + buf * 4096;
    gload16(gb, bs + t * 8);
    gload16(gb + (long)64 * 4096, bs + 2048 + t * 8);
  };

  stage(0, 0);
  __syncthreads();
  for (int kt = 0; kt < 128; ++kt) {
    const int cur = kt & 1;
    if (kt + 1 < 128) stage(cur ^ 1, (kt + 1) * 32);
    const unsigned short* ab =
        As + cur * 4096 + (wm * 64 + (lane & 15)) * 32 + (lane >> 4) * 8;
    const unsigned short* bb =
        Bs + cur * 4096 + (wn * 64 + (lane & 15)) * 32 + (lane >> 4) * 8;
    short8 af[4], bfr[4];
#pragma unroll
    for (int i = 0; i < 4; i++) af[i] = *(const short8*)(ab + i * 512);
#pragma unroll
    for (int i = 0; i < 4; i++) bfr[i] = *(const short8*)(bb + i * 512);
#pragma unroll
    for (int mi = 0; mi < 4; mi++)
#pragma unroll
      for (int ni = 0; ni < 4; ni++)
        acc[mi][ni] = __builtin_amdgcn_mfma_f32_16x16x32_bf16(
            af[mi], bfr[ni], acc[mi][ni], 0, 0, 0);
    __syncthreads();
  }
}

// ---------------------------------------------------------------- QKV projection
__global__ __launch_bounds__(256) void gemm_qkv(
    const unsigned short* __restrict__ A,   // hidden bf16 2048x4096
    const unsigned short* __restrict__ Wq,  // 4096x4096
    const unsigned short* __restrict__ Wk,  // 1024x4096
    const unsigned short* __restrict__ Wv,  // 1024x4096
    unsigned short* __restrict__ Qb,        // 2048x4096
    unsigned short* __restrict__ Kb,        // 2048x1024
    unsigned short* __restrict__ Vt) {      // 1024x2048 (transposed V)
  __shared__ unsigned short As[2 * 4096];
  __shared__ unsigned short Bs[2 * 4096];
  const int nb = blockIdx.x, mb = blockIdx.y;
  const unsigned short* Bp;
  int col0, mode;
  if (nb < 32)      { Bp = Wq; col0 = nb * 128;        mode = 0; }
  else if (nb < 40) { Bp = Wk; col0 = (nb - 32) * 128; mode = 1; }
  else              { Bp = Wv; col0 = (nb - 40) * 128; mode = 2; }
  const int mr0 = mb * 128;

  float4v acc[4][4];
  gemm128_core(A, Bp, mr0, col0, As, Bs, acc);

  const int lane = threadIdx.x & 63;
  const int wid = threadIdx.x >> 6;
  const int wm = wid >> 1, wn = wid & 1;
  const int lr = (lane >> 4) * 4, lc = lane & 15;
#pragma unroll
  for (int mi = 0; mi < 4; mi++)
#pragma unroll
    for (int ni = 0; ni < 4; ni++)
#pragma unroll
      for (int r = 0; r < 4; r++) {
        const int grow = mr0 + wm * 64 + mi * 16 + lr + r;
        const int gcol = col0 + wn * 64 + ni * 16 + lc;
        const unsigned short hv = f2bf(acc[mi][ni][r]);
        if (mode == 0)      Qb[(long)grow * 4096 + gcol] = hv;
        else if (mode == 1) Kb[(long)grow * 1024 + gcol] = hv;
        else                Vt[(long)gcol * 2048 + grow] = hv;
      }
}

// ---------------------------------------------------------------- output projection
__global__ __launch_bounds__(256) void gemm_out(
    const unsigned short* __restrict__ A,   // attn out bf16 2048x4096
    const unsigned short* __restrict__ W,   // Wo bf16 4096x4096
    float* __restrict__ C) {                // 2048x4096 f32
  __shared__ unsigned short As[2 * 4096];
  __shared__ unsigned short Bs[2 * 4096];
  const int nb = blockIdx.x, mb = blockIdx.y;
  const int col0 = nb * 128, mr0 = mb * 128;
  float4v acc[4][4];
  gemm128_core(A, W, mr0, col0, As, Bs, acc);
  const int lane = threadIdx.x & 63;
  const int wid = threadIdx.x >> 6;
  const int wm = wid >> 1, wn = wid & 1;
  const int lr = (lane >> 4) * 4, lc = lane & 15;
#pragma unroll
  for (int mi = 0; mi < 4; mi++)
#pragma unroll
    for (int ni = 0; ni < 4; ni++)
#pragma unroll
      for (int r = 0; r < 4; r++) {
        const int grow = mr0 + wm * 64 + mi * 16 + lr + r;
        const int gcol = col0 + wn * 64 + ni * 16 + lc;
        C[(long)grow * 4096 + gcol] = acc[mi][ni][r];
      }
}

// ---------------------------------------------------------------- RoPE (in place)
__global__ __launch_bounds__(256) void rope_kernel(
    unsigned short* __restrict__ Qb, unsigned short* __restrict__ Kb,
    const float* __restrict__ cosp, const float* __restrict__ sinp) {
  const long i = (long)blockIdx.x * 256 + threadIdx.x;
  unsigned short* buf;
  int nh;
  long j = i;
  if (j < 4194304) { buf = Qb; nh = 32; }
  else { j -= 4194304; buf = Kb; nh = 8; }
  const int d = (int)(j & 63);
  const long tmp = j >> 6;
  const int h = (int)(tmp % nh);
  const int s = (int)(tmp / nh);
  const long base = (long)s * nh * 128 + h * 128 + d;
  const float c = cosp[s * 128 + d];
  const float sn = sinp[s * 128 + d];
  const float x1 = bf2f(buf[base]);
  const float x2 = bf2f(buf[base + 64]);
  buf[base] = f2bf(x1 * c - x2 * sn);
  buf[base + 64] = f2bf(x2 * c + x1 * sn);
}

// ---------------------------------------------------------------- flash attention
// grid: 32 heads x 16 q-tile pairs. Each block handles q-tiles {31-pair, pair}
// (constant 33 tile-units of work). 4 waves, each owns 16 q rows of the
// 64-row q-tile. K (64x128) and Vt (128x64) tiles staged in LDS via
// global_load_lds, double-buffered, XOR-swizzled (linear LDS dest +
// inverse-swizzled global source + swizzled ds_read).
__global__ __launch_bounds__(256) void attn_kernel(
    const unsigned short* __restrict__ Q,   // 2048x4096 (roped)
    const unsigned short* __restrict__ K,   // 2048x1024 (roped)
    const unsigned short* __restrict__ Vt,  // 1024x2048
    unsigned short* __restrict__ AO) {      // 2048x4096
  __shared__ unsigned short Ks[2][8192];        // 64 rows x 256B, swizzled
  __shared__ unsigned short Vs[2][8192];        // 128 rows x 128B, swizzled
  __shared__ unsigned short P_lds[4][16][72];   // per wave, padded
  const int t = threadIdx.x, lane = t & 63, w = t >> 6;
  const int hq = blockIdx.x >> 4;
  const int pair = blockIdx.x & 15;
  const int hkv = hq >> 2;
  const int lc = lane & 15, lg = lane >> 4;
  const float scale = 0.08838834764831845f;  // 1/sqrt(128)

  // stage K tile (rows c0..c0+63, 128 head cols) into swizzled LDS
  auto stageK = [&](unsigned short* ks, int c0) {
#pragma unroll
    for (int i = 0; i < 4; i++) {
      const int o = (t + i * 256) * 16;          // linear LDS byte offset
      const int row = o >> 8;                    // 256B per row
      const int scb = (o & 255) ^ ((row & 7) << 4);
      gload16(K + (long)(c0 + row) * 1024 + hkv * 128 + (scb >> 1),
              (char*)ks + o);
    }
  };
  // stage Vt tile (128 d-rows, 64 s-cols) into swizzled LDS
  auto stageV = [&](unsigned short* vs, int c0) {
#pragma unroll
    for (int i = 0; i < 4; i++) {
      const int o = (t + i * 256) * 16;
      const int row = o >> 7;                    // 128B per row
      const int scb = (o & 127) ^ ((row & 7) << 4);
      gload16(Vt + (long)(hkv * 128 + row) * 2048 + c0 + (scb >> 1),
              (char*)vs + o);
    }
  };

  for (int half = 0; half < 2; ++half) {
    const int qt = half ? pair : (31 - pair);   // long tile first
    const int qr0 = qt * 64 + w * 16;
    const int ntiles = qt + 1;

    // Q fragments (hoisted per pass)
    short8 aq[4];
    const unsigned short* qbase = Q + (long)(qr0 + lc) * 4096 + hq * 128 + lg * 8;
#pragma unroll
    for (int kk = 0; kk < 4; kk++) aq[kk] = *(const short8*)(qbase + kk * 32);

    float m_i[4], l_i[4];
    float4v acc_o[8];
#pragma unroll
    for (int r = 0; r < 4; r++) { m_i[r] = -1e30f; l_i[r] = 0.f; }
#pragma unroll
    for (int n = 0; n < 8; n++) acc_o[n] = (float4v){0.f, 0.f, 0.f, 0.f};

    stageK(Ks[0], 0);
    stageV(Vs[0], 0);
    __syncthreads();

    for (int it = 0; it < ntiles; ++it) {
      const int cur = it & 1;
      if (it + 1 < ntiles) {
        stageK(Ks[cur ^ 1], (it + 1) * 64);
        stageV(Vs[cur ^ 1], (it + 1) * 64);
      }
      const char* ks = (const char*)Ks[cur];
      const char* vs = (const char*)Vs[cur];

      // ---- S = Q K^T (16x64)
      float4v accs[4];
#pragma unroll
      for (int n = 0; n < 4; n++) accs[n] = (float4v){0.f, 0.f, 0.f, 0.f};
#pragma unroll
      for (int n = 0; n < 4; n++) {
        const int row = n * 16 + lc;
        const int sx = (row & 7) << 4;
#pragma unroll
        for (int kk = 0; kk < 4; kk++) {
          short8 bk = *(const short8*)(ks + row * 256 + ((kk * 64 + lg * 16) ^ sx));
          accs[n] = __builtin_amdgcn_mfma_f32_16x16x32_bf16(aq[kk], bk, accs[n], 0, 0, 0);
        }
      }
      // ---- scale (+ causal mask only on the diagonal tile)
      if (it == qt) {
#pragma unroll
        for (int n = 0; n < 4; n++) {
          const int gcol = it * 64 + n * 16 + lc;
#pragma unroll
          for (int r = 0; r < 4; r++) {
            const int grow = qr0 + lg * 4 + r;
            const float sv = accs[n][r] * scale;
            accs[n][r] = (gcol > grow) ? -1e30f : sv;
          }
        }
      } else {
#pragma unroll
        for (int n = 0; n < 4; n++)
#pragma unroll
          for (int r = 0; r < 4; r++) accs[n][r] *= scale;
      }
      // ---- online softmax (rows live in 16-lane groups)
      float sc[4];
#pragma unroll
      for (int r = 0; r < 4; r++) {
        float vm = fmaxf(fmaxf(accs[0][r], accs[1][r]), fmaxf(accs[2][r], accs[3][r]));
#pragma unroll
        for (int x = 1; x < 16; x <<= 1) vm = fmaxf(vm, __shfl_xor(vm, x, 64));
        const float mn = fmaxf(m_i[r], vm);
        sc[r] = __expf(m_i[r] - mn);
        m_i[r] = mn;
        float rs = 0.f;
#pragma unroll
        for (int n = 0; n < 4; n++) {
          const float pv = __expf(accs[n][r] - mn);
          accs[n][r] = pv;
          rs += pv;
        }
#pragma unroll
        for (int x = 1; x < 16; x <<= 1) rs += __shfl_xor(rs, x, 64);
        l_i[r] = l_i[r] * sc[r] + rs;
      }
#pragma unroll
      for (int n = 0; n < 8; n++)
#pragma unroll
        for (int r = 0; r < 4; r++) acc_o[n][r] *= sc[r];
      // ---- P -> LDS (bf16), per-wave private (in-order DS pipe, no barrier)
#pragma unroll
      for (int n = 0; n < 4; n++)
#pragma unroll
        for (int r = 0; r < 4; r++)
          P_lds[w][lg * 4 + r][n * 16 + lc] = f2bf(accs[n][r]);
      // ---- O += P V
#pragma unroll
      for (int kk = 0; kk < 2; kk++) {
        short8 ap = *(const short8*)&P_lds[w][lc][kk * 32 + lg * 8];
#pragma unroll
        for (int nd = 0; nd < 8; nd++) {
          const int row = nd * 16 + lc;
          const int cb = (kk * 64 + lg * 16) ^ ((row & 7) << 4);
          short8 bv = *(const short8*)(vs + row * 128 + cb);
          acc_o[nd] = __builtin_amdgcn_mfma_f32_16x16x32_bf16(ap, bv, acc_o[nd], 0, 0, 0);
        }
      }
      __syncthreads();
    }
    // ---- epilogue
#pragma unroll
    for (int nd = 0; nd < 8; nd++)
#pragma unroll
      for (int r = 0; r < 4; r++) {
        const float o = acc_o[nd][r] / l_i[r];
        const int grow = qr0 + lg * 4 + r;
        AO[(long)grow * 4096 + hq * 128 + nd * 16 + lc] = f2bf(o);
      }
  }
}

// ---------------------------------------------------------------- launch
extern "C" void kernel_launch(void* const* d_in, const int* in_sizes, int n_in,
                              void* d_out, int out_size, void* d_ws, size_t ws_size,
                              hipStream_t stream) {
  const float* hidden = (const float*)d_in[0];
  const float* cosp   = (const float*)d_in[1];
  const float* sinp   = (const float*)d_in[2];
  // d_in[3] = attention_mask (pure causal, implemented analytically)
  const float* Wq = (const float*)d_in[4];
  const float* Wk = (const float*)d_in[5];
  const float* Wv = (const float*)d_in[6];
  const float* Wo = (const float*)d_in[7];
  float* out = (float*)d_out;

  char* ws = (char*)d_ws;
  unsigned short* hidB = (unsigned short*)(ws + 0);          // 16 MiB
  unsigned short* WqB  = (unsigned short*)(ws + 16777216);   // 32 MiB
  unsigned short* WkB  = (unsigned short*)(ws + 50331648);   // 8 MiB
  unsigned short* WvB  = (unsigned short*)(ws + 58720256);   // 8 MiB
  unsigned short* WoB  = (unsigned short*)(ws + 67108864);   // 32 MiB
  unsigned short* Qb   = (unsigned short*)(ws + 100663296);  // 16 MiB
  unsigned short* Kb   = (unsigned short*)(ws + 117440512);  // 4 MiB
  unsigned short* VtB  = (unsigned short*)(ws + 121634816);  // 4 MiB
  unsigned short* AO   = (unsigned short*)(ws + 125829120);  // 16 MiB
  // total 142,606,336 bytes

  cast_all<<<2048, 256, 0, stream>>>(hidden, Wq, Wk, Wv, Wo,
                                     hidB, WqB, WkB, WvB, WoB);
  gemm_qkv<<<dim3(48, 16), 256, 0, stream>>>(hidB, WqB, WkB, WvB, Qb, Kb, VtB);
  rope_kernel<<<20480, 256, 0, stream>>>(Qb, Kb, cosp, sinp);
  attn_kernel<<<512, 256, 0, stream>>>(Qb, Kb, VtB, AO);
  gemm_out<<<dim3(32, 16), 256, 0, stream>>>(AO, WoB, out);
}

// Round 4
// 530.771 us; speedup vs baseline: 1.7363x; 1.0814x over previous
//
#include <hip/hip_runtime.h>
#include <cstdint>

typedef __attribute__((ext_vector_type(8))) short short8;
typedef __attribute__((ext_vector_type(4))) float float4v;

#define S_LEN 2048
#define HIDDIM 4096

static __device__ __forceinline__ unsigned short f2bf(float f) {
  unsigned int u = __float_as_uint(f);
  unsigned int r = (u + 0x7FFFu + ((u >> 16) & 1u)) >> 16;
  return (unsigned short)r;
}
static __device__ __forceinline__ float bf2f(unsigned short h) {
  return __uint_as_float(((unsigned int)h) << 16);
}

static __device__ __forceinline__ void gload16(const void* gp, void* lp) {
  __builtin_amdgcn_global_load_lds(
      (const __attribute__((address_space(1))) void*)gp,
      (__attribute__((address_space(3))) void*)lp, 16, 0, 0);
}

// ---------------------------------------------------------------- cast f32->bf16
__global__ __launch_bounds__(256) void cast_all(
    const float* __restrict__ s0, const float* __restrict__ s1,
    const float* __restrict__ s2, const float* __restrict__ s3,
    const float* __restrict__ s4,
    unsigned short* __restrict__ d0, unsigned short* __restrict__ d1,
    unsigned short* __restrict__ d2, unsigned short* __restrict__ d3,
    unsigned short* __restrict__ d4) {
  const long n0 = 2097152, n1 = 4194304, n2 = 1048576, n3 = 1048576, n4 = 4194304;
  const long total = n0 + n1 + n2 + n3 + n4;  // 12582912
  for (long i = (long)blockIdx.x * 256 + threadIdx.x; i < total;
       i += (long)gridDim.x * 256) {
    const float* src; unsigned short* dst; long j = i;
    if (j < n0) { src = s0; dst = d0; }
    else if ((j -= n0) < n1) { src = s1; dst = d1; }
    else if ((j -= n1) < n2) { src = s2; dst = d2; }
    else if ((j -= n2) < n3) { src = s3; dst = d3; }
    else { j -= n3; src = s4; dst = d4; }
    float4 v = reinterpret_cast<const float4*>(src)[j];
    ushort4 o;
    o.x = f2bf(v.x); o.y = f2bf(v.y); o.z = f2bf(v.z); o.w = f2bf(v.w);
    reinterpret_cast<ushort4*>(dst)[j] = o;
  }
}

// ---------------------------------------------------------------- GEMM core
// C[M,N] = A[M,K] * B[N,K]^T, K=4096, 128x128 tile, BK=32, 4 waves (2x2),
// 16x16x32 bf16 MFMA. Triple-buffered LDS ring (48 KB), counted vmcnt
// (never 0 in steady state), one raw s_barrier per K-tile, XOR bank swizzle
// (granule ^= row&3) applied on the pre-swizzled global source of
// global_load_lds (linear LDS dest) and on the swizzled ds_read address.
__device__ __forceinline__ void gemm_core128(
    const unsigned short* __restrict__ A, const unsigned short* __restrict__ B,
    int mr0, int nc0, unsigned short* As, unsigned short* Bs,
    float4v acc[4][4]) {
  const int t0 = threadIdx.x;
  const int lane = t0 & 63;
  const int w = t0 >> 6;
  const int wm = w >> 1, wn = w & 1;

  // staging: thread t0 (+round i in {0,1}) covers linear LDS bytes
  // o = (t0 + i*256)*16 of an 8 KB tile. row = o>>6 (64 B rows),
  // source k-granule = ((o>>4)&3) ^ (row&3)  (the swizzle involution).
  const int rowA = t0 >> 2;                       // i=0 row; i=1 is rowA+64
  const int gsw = (((t0 & 3) ^ (rowA & 3))) * 8;  // swizzled k-elem offset
  const unsigned short* aSrc = A + (long)(mr0 + rowA) * 4096 + gsw;
  const unsigned short* bSrc = B + (long)(nc0 + rowA) * 4096 + gsw;
  unsigned short* aDst = As + t0 * 8;
  unsigned short* bDst = Bs + t0 * 8;

  // ds_read lane offset: row=(lane&15) within frag, granule=(lane>>4)^(lane&3)
  const int lsw = ((((lane >> 4) ^ (lane & 3)) << 4) | ((lane & 15) << 6));
  const char* aRd = (const char*)As + lsw + (wm << 12);  // + wm*64 rows
  const char* bRd = (const char*)Bs + lsw + (wn << 12);

#pragma unroll
  for (int i = 0; i < 4; i++)
#pragma unroll
    for (int j = 0; j < 4; j++) acc[i][j] = (float4v){0.f, 0.f, 0.f, 0.f};

  auto stage = [&](int b, int kt) {
    const int ko = kt * 32;
    gload16(aSrc + ko, aDst + b * 4096);
    gload16(aSrc + ko + 64 * 4096, aDst + b * 4096 + 2048);
    gload16(bSrc + ko, bDst + b * 4096);
    gload16(bSrc + ko + 64 * 4096, bDst + b * 4096 + 2048);
  };
  stage(0, 0);
  stage(1, 1);

  for (int t = 0; t < 128; ++t) {
    // tile t's 4 loads are the oldest; allow tile t+1's 4 to stay in flight
    if (t < 127) asm volatile("s_waitcnt vmcnt(4)" ::: "memory");
    else         asm volatile("s_waitcnt vmcnt(0)" ::: "memory");
    __builtin_amdgcn_s_barrier();
    __builtin_amdgcn_sched_barrier(0);
    const int b = t % 3;
    short8 af[4], bfv[4];
#pragma unroll
    for (int mi = 0; mi < 4; mi++)
      af[mi] = *(const short8*)(aRd + b * 8192 + mi * 1024);
#pragma unroll
    for (int ni = 0; ni < 4; ni++)
      bfv[ni] = *(const short8*)(bRd + b * 8192 + ni * 1024);
    // prefetch tile t+2 into the buffer last read at tile t-1 (WAR-safe:
    // issued after barrier t, which follows all waves' t-1 reads)
    if (t + 2 < 128) stage((t + 2) % 3, t + 2);
    __builtin_amdgcn_s_setprio(1);
#pragma unroll
    for (int mi = 0; mi < 4; mi++)
#pragma unroll
      for (int ni = 0; ni < 4; ni++)
        acc[mi][ni] = __builtin_amdgcn_mfma_f32_16x16x32_bf16(
            af[mi], bfv[ni], acc[mi][ni], 0, 0, 0);
    __builtin_amdgcn_s_setprio(0);
  }
}

// ---------------------------------------------------------------- QKV projection
__global__ __launch_bounds__(256) void gemm_qkv(
    const unsigned short* __restrict__ A,   // hidden bf16 2048x4096
    const unsigned short* __restrict__ Wq,  // 4096x4096
    const unsigned short* __restrict__ Wk,  // 1024x4096
    const unsigned short* __restrict__ Wv,  // 1024x4096
    unsigned short* __restrict__ Qb,        // 2048x4096
    unsigned short* __restrict__ Kb,        // 2048x1024
    unsigned short* __restrict__ Vt) {      // 1024x2048 (transposed V)
  __shared__ unsigned short As[3 * 4096];
  __shared__ unsigned short Bs[3 * 4096];
  const int nb = blockIdx.x, mb = blockIdx.y;
  const unsigned short* Bp;
  int col0, mode;
  if (nb < 32)      { Bp = Wq; col0 = nb * 128;        mode = 0; }
  else if (nb < 40) { Bp = Wk; col0 = (nb - 32) * 128; mode = 1; }
  else              { Bp = Wv; col0 = (nb - 40) * 128; mode = 2; }
  const int mr0 = mb * 128;

  float4v acc[4][4];
  gemm_core128(A, Bp, mr0, col0, As, Bs, acc);

  const int lane = threadIdx.x & 63;
  const int wid = threadIdx.x >> 6;
  const int wm = wid >> 1, wn = wid & 1;
  const int lr = (lane >> 4) * 4, lc = lane & 15;
#pragma unroll
  for (int mi = 0; mi < 4; mi++)
#pragma unroll
    for (int ni = 0; ni < 4; ni++)
#pragma unroll
      for (int r = 0; r < 4; r++) {
        const int grow = mr0 + wm * 64 + mi * 16 + lr + r;
        const int gcol = col0 + wn * 64 + ni * 16 + lc;
        const unsigned short hv = f2bf(acc[mi][ni][r]);
        if (mode == 0)      Qb[(long)grow * 4096 + gcol] = hv;
        else if (mode == 1) Kb[(long)grow * 1024 + gcol] = hv;
        else                Vt[(long)gcol * 2048 + grow] = hv;
      }
}

// ---------------------------------------------------------------- output projection
__global__ __launch_bounds__(256) void gemm_out(
    const unsigned short* __restrict__ A,   // attn out bf16 2048x4096
    const unsigned short* __restrict__ W,   // Wo bf16 4096x4096
    float* __restrict__ C) {                // 2048x4096 f32
  __shared__ unsigned short As[3 * 4096];
  __shared__ unsigned short Bs[3 * 4096];
  const int nb = blockIdx.x, mb = blockIdx.y;
  const int col0 = nb * 128, mr0 = mb * 128;
  float4v acc[4][4];
  gemm_core128(A, W, mr0, col0, As, Bs, acc);
  const int lane = threadIdx.x & 63;
  const int wid = threadIdx.x >> 6;
  const int wm = wid >> 1, wn = wid & 1;
  const int lr = (lane >> 4) * 4, lc = lane & 15;
#pragma unroll
  for (int mi = 0; mi < 4; mi++)
#pragma unroll
    for (int ni = 0; ni < 4; ni++)
#pragma unroll
      for (int r = 0; r < 4; r++) {
        const int grow = mr0 + wm * 64 + mi * 16 + lr + r;
        const int gcol = col0 + wn * 64 + ni * 16 + lc;
        C[(long)grow * 4096 + gcol] = acc[mi][ni][r];
      }
}

// ---------------------------------------------------------------- RoPE (in place)
__global__ __launch_bounds__(256) void rope_kernel(
    unsigned short* __restrict__ Qb, unsigned short* __restrict__ Kb,
    const float* __restrict__ cosp, const float* __restrict__ sinp) {
  const long i = (long)blockIdx.x * 256 + threadIdx.x;
  unsigned short* buf;
  int nh;
  long j = i;
  if (j < 4194304) { buf = Qb; nh = 32; }
  else { j -= 4194304; buf = Kb; nh = 8; }
  const int d = (int)(j & 63);
  const long tmp = j >> 6;
  const int h = (int)(tmp % nh);
  const int s = (int)(tmp / nh);
  const long base = (long)s * nh * 128 + h * 128 + d;
  const float c = cosp[s * 128 + d];
  const float sn = sinp[s * 128 + d];
  const float x1 = bf2f(buf[base]);
  const float x2 = bf2f(buf[base + 64]);
  buf[base] = f2bf(x1 * c - x2 * sn);
  buf[base + 64] = f2bf(x2 * c + x1 * sn);
}

// ---------------------------------------------------------------- flash attention
// grid: 32 heads x 16 q-tile pairs. Each block handles q-tiles {31-pair, pair}
// (constant 33 tile-units of work). 4 waves, each owns 16 q rows of the
// 64-row q-tile. K (64x128) and Vt (128x64) tiles staged in LDS via
// global_load_lds, double-buffered, XOR-swizzled (linear LDS dest +
// inverse-swizzled global source + swizzled ds_read).
__global__ __launch_bounds__(256) void attn_kernel(
    const unsigned short* __restrict__ Q,   // 2048x4096 (roped)
    const unsigned short* __restrict__ K,   // 2048x1024 (roped)
    const unsigned short* __restrict__ Vt,  // 1024x2048
    unsigned short* __restrict__ AO) {      // 2048x4096
  __shared__ unsigned short Ks[2][8192];        // 64 rows x 256B, swizzled
  __shared__ unsigned short Vs[2][8192];        // 128 rows x 128B, swizzled
  __shared__ unsigned short P_lds[4][16][72];   // per wave, padded
  const int t = threadIdx.x, lane = t & 63, w = t >> 6;
  const int hq = blockIdx.x >> 4;
  const int pair = blockIdx.x & 15;
  const int hkv = hq >> 2;
  const int lc = lane & 15, lg = lane >> 4;
  const float scale = 0.08838834764831845f;  // 1/sqrt(128)

  // stage K tile (rows c0..c0+63, 128 head cols) into swizzled LDS
  auto stageK = [&](unsigned short* ks, int c0) {
#pragma unroll
    for (int i = 0; i < 4; i++) {
      const int o = (t + i * 256) * 16;          // linear LDS byte offset
      const int row = o >> 8;                    // 256B per row
      const int scb = (o & 255) ^ ((row & 7) << 4);
      gload16(K + (long)(c0 + row) * 1024 + hkv * 128 + (scb >> 1),
              (char*)ks + o);
    }
  };
  // stage Vt tile (128 d-rows, 64 s-cols) into swizzled LDS
  auto stageV = [&](unsigned short* vs, int c0) {
#pragma unroll
    for (int i = 0; i < 4; i++) {
      const int o = (t + i * 256) * 16;
      const int row = o >> 7;                    // 128B per row
      const int scb = (o & 127) ^ ((row & 7) << 4);
      gload16(Vt + (long)(hkv * 128 + row) * 2048 + c0 + (scb >> 1),
              (char*)vs + o);
    }
  };

  for (int half = 0; half < 2; ++half) {
    const int qt = half ? pair : (31 - pair);   // long tile first
    const int qr0 = qt * 64 + w * 16;
    const int ntiles = qt + 1;

    // Q fragments (hoisted per pass)
    short8 aq[4];
    const unsigned short* qbase = Q + (long)(qr0 + lc) * 4096 + hq * 128 + lg * 8;
#pragma unroll
    for (int kk = 0; kk < 4; kk++) aq[kk] = *(const short8*)(qbase + kk * 32);

    float m_i[4], l_i[4];
    float4v acc_o[8];
#pragma unroll
    for (int r = 0; r < 4; r++) { m_i[r] = -1e30f; l_i[r] = 0.f; }
#pragma unroll
    for (int n = 0; n < 8; n++) acc_o[n] = (float4v){0.f, 0.f, 0.f, 0.f};

    stageK(Ks[0], 0);
    stageV(Vs[0], 0);
    __syncthreads();

    for (int it = 0; it < ntiles; ++it) {
      const int cur = it & 1;
      if (it + 1 < ntiles) {
        stageK(Ks[cur ^ 1], (it + 1) * 64);
        stageV(Vs[cur ^ 1], (it + 1) * 64);
      }
      const char* ks = (const char*)Ks[cur];
      const char* vs = (const char*)Vs[cur];

      // ---- S = Q K^T (16x64)
      float4v accs[4];
#pragma unroll
      for (int n = 0; n < 4; n++) accs[n] = (float4v){0.f, 0.f, 0.f, 0.f};
#pragma unroll
      for (int n = 0; n < 4; n++) {
        const int row = n * 16 + lc;
        const int sx = (row & 7) << 4;
#pragma unroll
        for (int kk = 0; kk < 4; kk++) {
          short8 bk = *(const short8*)(ks + row * 256 + ((kk * 64 + lg * 16) ^ sx));
          accs[n] = __builtin_amdgcn_mfma_f32_16x16x32_bf16(aq[kk], bk, accs[n], 0, 0, 0);
        }
      }
      // ---- scale (+ causal mask only on the diagonal tile)
      if (it == qt) {
#pragma unroll
        for (int n = 0; n < 4; n++) {
          const int gcol = it * 64 + n * 16 + lc;
#pragma unroll
          for (int r = 0; r < 4; r++) {
            const int grow = qr0 + lg * 4 + r;
            const float sv = accs[n][r] * scale;
            accs[n][r] = (gcol > grow) ? -1e30f : sv;
          }
        }
      } else {
#pragma unroll
        for (int n = 0; n < 4; n++)
#pragma unroll
          for (int r = 0; r < 4; r++) accs[n][r] *= scale;
      }
      // ---- online softmax (rows live in 16-lane groups)
      float sc[4];
#pragma unroll
      for (int r = 0; r < 4; r++) {
        float vm = fmaxf(fmaxf(accs[0][r], accs[1][r]), fmaxf(accs[2][r], accs[3][r]));
#pragma unroll
        for (int x = 1; x < 16; x <<= 1) vm = fmaxf(vm, __shfl_xor(vm, x, 64));
        const float mn = fmaxf(m_i[r], vm);
        sc[r] = __expf(m_i[r] - mn);
        m_i[r] = mn;
        float rs = 0.f;
#pragma unroll
        for (int n = 0; n < 4; n++) {
          const float pv = __expf(accs[n][r] - mn);
          accs[n][r] = pv;
          rs += pv;
        }
#pragma unroll
        for (int x = 1; x < 16; x <<= 1) rs += __shfl_xor(rs, x, 64);
        l_i[r] = l_i[r] * sc[r] + rs;
      }
#pragma unroll
      for (int n = 0; n < 8; n++)
#pragma unroll
        for (int r = 0; r < 4; r++) acc_o[n][r] *= sc[r];
      // ---- P -> LDS (bf16), per-wave private (in-order DS pipe, no barrier)
#pragma unroll
      for (int n = 0; n < 4; n++)
#pragma unroll
        for (int r = 0; r < 4; r++)
          P_lds[w][lg * 4 + r][n * 16 + lc] = f2bf(accs[n][r]);
      // ---- O += P V
#pragma unroll
      for (int kk = 0; kk < 2; kk++) {
        short8 ap = *(const short8*)&P_lds[w][lc][kk * 32 + lg * 8];
#pragma unroll
        for (int nd = 0; nd < 8; nd++) {
          const int row = nd * 16 + lc;
          const int cb = (kk * 64 + lg * 16) ^ ((row & 7) << 4);
          short8 bv = *(const short8*)(vs + row * 128 + cb);
          acc_o[nd] = __builtin_amdgcn_mfma_f32_16x16x32_bf16(ap, bv, acc_o[nd], 0, 0, 0);
        }
      }
      __syncthreads();
    }
    // ---- epilogue
#pragma unroll
    for (int nd = 0; nd < 8; nd++)
#pragma unroll
      for (int r = 0; r < 4; r++) {
        const float o = acc_o[nd][r] / l_i[r];
        const int grow = qr0 + lg * 4 + r;
        AO[(long)grow * 4096 + hq * 128 + nd * 16 + lc] = f2bf(o);
      }
  }
}

// ---------------------------------------------------------------- launch
extern "C" void kernel_launch(void* const* d_in, const int* in_sizes, int n_in,
                              void* d_out, int out_size, void* d_ws, size_t ws_size,
                              hipStream_t stream) {
  const float* hidden = (const float*)d_in[0];
  const float* cosp   = (const float*)d_in[1];
  const float* sinp   = (const float*)d_in[2];
  // d_in[3] = attention_mask (pure causal, implemented analytically)
  const float* Wq = (const float*)d_in[4];
  const float* Wk = (const float*)d_in[5];
  const float* Wv = (const float*)d_in[6];
  const float* Wo = (const float*)d_in[7];
  float* out = (float*)d_out;

  char* ws = (char*)d_ws;
  unsigned short* hidB = (unsigned short*)(ws + 0);          // 16 MiB
  unsigned short* WqB  = (unsigned short*)(ws + 16777216);   // 32 MiB
  unsigned short* WkB  = (unsigned short*)(ws + 50331648);   // 8 MiB
  unsigned short* WvB  = (unsigned short*)(ws + 58720256);   // 8 MiB
  unsigned short* WoB  = (unsigned short*)(ws + 67108864);   // 32 MiB
  unsigned short* Qb   = (unsigned short*)(ws + 100663296);  // 16 MiB
  unsigned short* Kb   = (unsigned short*)(ws + 117440512);  // 4 MiB
  unsigned short* VtB  = (unsigned short*)(ws + 121634816);  // 4 MiB
  unsigned short* AO   = (unsigned short*)(ws + 125829120);  // 16 MiB
  // total 142,606,336 bytes

  cast_all<<<2048, 256, 0, stream>>>(hidden, Wq, Wk, Wv, Wo,
                                     hidB, WqB, WkB, WvB, WoB);
  gemm_qkv<<<dim3(48, 16), 256, 0, stream>>>(hidB, WqB, WkB, WvB, Qb, Kb, VtB);
  rope_kernel<<<20480, 256, 0, stream>>>(Qb, Kb, cosp, sinp);
  attn_kernel<<<512, 256, 0, stream>>>(Qb, Kb, VtB, AO);
  gemm_out<<<dim3(32, 16), 256, 0, stream>>>(AO, WoB, out);
}